// Round 5
// baseline (1033.132 us; speedup 1.0000x reference)
//
#include <hip/hip_runtime.h>

// Correlation layer, MAX_DISP=4: out[b, dx*9+dy, h, w] =
//   mean_c x1[b,c,h,w] * x2[b,c,h+dx-4,w+dy-4]  (x2 zero-padded)
// x1,x2: (8,64,256,256) fp32.  out: (8,81,256,256) fp32.
//
// R5: latency attack. R1-R4 all plateau ~230-270us with VALUBusy<37%,
// occupancy<43%, HBM<15% -> latency-bound (per-channel: 144cy FMA vs
// 220-600cy L2/L3 hit latency, prefetch distance was 1 channel).
// Fix: explicit 2-deep channel prefetch ring (named bufs, static idx),
// so loads are issued ~2 compute blocks before consumption.
// Keeps: VW=8 split-wave (lanes 0-31 row h, 32-63 row h+1; x2 window
// w0-4..w0+11 = exactly 4 float4, no halo waste), 1-wave blocks,
// XCD swizzle (b = blockIdx&7).

namespace {
constexpr int kB = 8;
constexpr int kC = 64;
constexpr int kH = 256;
constexpr int kW = 256;
constexpr int kD = 9;          // 2*4+1
constexpr int kMD = 4;
constexpr int kCS = kH * kW;   // channel stride
}  // namespace

__global__ __launch_bounds__(64) void corr_kernel(
    const float* __restrict__ x1, const float* __restrict__ x2,
    float* __restrict__ out) {
  // XCD-locality decode (grid = 8 * 128 * 9, multiple of 8)
  const int xcd  = blockIdx.x & 7;
  const int slot = blockIdx.x >> 3;        // sequential on one XCD
  const int b  = xcd;
  const int hp = slot / kD;                // 0..127 (pair of rows)
  const int dx = slot - hp * kD;

  const int lane = (int)threadIdx.x;
  const int half = lane >> 5;              // 0: row h0, 1: row h0+1
  const int lh   = lane & 31;
  const int h    = hp * 2 + half;
  const int row  = h + dx - kMD;           // x2 source row (may be OOB)
  const int w0   = lh * 8;

  const bool rowok = (row >= 0) && (row < kH);
  const bool hasL  = rowok && (lh > 0);
  const bool hasR  = rowok && (lh < 31);

  float acc[kD][8];
#pragma unroll
  for (int dy = 0; dy < kD; ++dy)
#pragma unroll
    for (int j = 0; j < 8; ++j) acc[dy][j] = 0.0f;

  const float* p1 = x1 + ((size_t)(b * kC) * kH + h) * kW + w0;
  const float* p2 = x2 + ((size_t)(b * kC) * kH + row) * kW + w0;
  const float4 z = make_float4(0.f, 0.f, 0.f, 0.f);

  // two named prefetch buffers (all indexing static -> stays in VGPRs)
  float4 Aa0, Aa1, At0, At1, At2, At3;
  float4 Ba0, Ba1, Bt0, Bt1, Bt2, Bt3;

#define LDBUF(P0, P1, P2, P3, P4, P5, q1, q2)                        \
  do {                                                               \
    P0 = *reinterpret_cast<const float4*>(q1);                       \
    P1 = *reinterpret_cast<const float4*>((q1) + 4);                 \
    P2 = hasL  ? *reinterpret_cast<const float4*>((q2) - 4) : z;     \
    P3 = rowok ? *reinterpret_cast<const float4*>(q2)       : z;     \
    P4 = rowok ? *reinterpret_cast<const float4*>((q2) + 4) : z;     \
    P5 = hasR  ? *reinterpret_cast<const float4*>((q2) + 8) : z;     \
  } while (0)

#define FMABUF(P0, P1, P2, P3, P4, P5)                               \
  do {                                                               \
    const float av[8] = {P0.x, P0.y, P0.z, P0.w,                     \
                         P1.x, P1.y, P1.z, P1.w};                    \
    const float t[16] = {P2.x, P2.y, P2.z, P2.w,                     \
                         P3.x, P3.y, P3.z, P3.w,                     \
                         P4.x, P4.y, P4.z, P4.w,                     \
                         P5.x, P5.y, P5.z, P5.w};                    \
    _Pragma("unroll")                                                \
    for (int dy = 0; dy < kD; ++dy)                                  \
      _Pragma("unroll")                                              \
      for (int j = 0; j < 8; ++j)                                    \
        acc[dy][j] = fmaf(av[j], t[dy + j], acc[dy][j]);             \
  } while (0)

  // prologue: channels 0 and 1 in flight
  LDBUF(Aa0, Aa1, At0, At1, At2, At3, p1, p2);
  LDBUF(Ba0, Ba1, Bt0, Bt1, Bt2, Bt3, p1 + kCS, p2 + kCS);

  // steady state: compute c, issue c+2 (distance-2 prefetch)
  for (int c = 0; c < kC - 2; c += 2) {
    FMABUF(Aa0, Aa1, At0, At1, At2, At3);
    LDBUF(Aa0, Aa1, At0, At1, At2, At3, p1 + 2 * kCS, p2 + 2 * kCS);
    FMABUF(Ba0, Ba1, Bt0, Bt1, Bt2, Bt3);
    LDBUF(Ba0, Ba1, Bt0, Bt1, Bt2, Bt3, p1 + 3 * kCS, p2 + 3 * kCS);
    p1 += 2 * kCS;
    p2 += 2 * kCS;
  }
  // tail: channels 62, 63
  FMABUF(Aa0, Aa1, At0, At1, At2, At3);
  FMABUF(Ba0, Ba1, Bt0, Bt1, Bt2, Bt3);

#undef LDBUF
#undef FMABUF

  const float inv = 1.0f / (float)kC;
  float* po = out + (((size_t)b * (kD * kD) + dx * kD) * kH + h) * kW + w0;
#pragma unroll
  for (int dy = 0; dy < kD; ++dy) {
    float4 o0 = make_float4(acc[dy][0] * inv, acc[dy][1] * inv,
                            acc[dy][2] * inv, acc[dy][3] * inv);
    float4 o1 = make_float4(acc[dy][4] * inv, acc[dy][5] * inv,
                            acc[dy][6] * inv, acc[dy][7] * inv);
    *reinterpret_cast<float4*>(po)     = o0;
    *reinterpret_cast<float4*>(po + 4) = o1;
    po += (size_t)kH * kW;
  }
}

extern "C" void kernel_launch(void* const* d_in, const int* in_sizes, int n_in,
                              void* d_out, int out_size, void* d_ws, size_t ws_size,
                              hipStream_t stream) {
  const float* x1 = (const float*)d_in[0];
  const float* x2 = (const float*)d_in[1];
  float* out = (float*)d_out;
  const int grid = kB * (kH / 2) * kD;  // 9216 blocks, 1 wave each
  corr_kernel<<<grid, 64, 0, stream>>>(x1, x2, out);
}

// Round 6
// 476.851 us; speedup vs baseline: 2.1666x; 2.1666x over previous
//
#include <hip/hip_runtime.h>

// Correlation, MAX_DISP=4: out[b, dx*9+dy, h, w] =
//   mean_c x1[b,c,h,w] * x2[b,c,h+dx-4,w+dy-4] (x2 zero-padded)
// x1,x2: (8,64,256,256) fp32. out: (8,81,256,256) fp32.
//
// R6: LDS-staged 9-wave block. Block = (b, h-pair), wave wv = dx (0..8).
// Per channel, 12 rows (2 x1 + 10 x2 = rows 2hp-4..2hp+5) staged into
// double-buffered LDS (12 KB/buf); each row read ~9x from LDS instead of
// L1/L2 -> global traffic drops 9x (this was the R1-R4 floor).
// Lane split: lanes 0-31 output row h0, 32-63 row h1, VW=8.
// Bank swizzle: 16B-block b within a 1KB row stored at b^((b>>3)&7)
// (involution, applied write+read) -> stride-32B window reads hit all 8
// bank groups = conflict-free floor. One barrier per channel.

namespace {
constexpr int kB = 8;
constexpr int kC = 64;
constexpr int kH = 256;
constexpr int kW = 256;
constexpr int kD = 9;             // 2*4+1
constexpr int kCS = kH * kW;      // channel stride (elements)
constexpr int kRows = 12;         // 2 x1 + 10 x2 rows per channel
constexpr int kBufDw = kRows * kW;  // 3072 dwords = 12 KB
}  // namespace

__device__ __forceinline__ int swz(int b) { return b ^ ((b >> 3) & 7); }

__global__ __launch_bounds__(576) void corr_kernel(
    const float* __restrict__ x1, const float* __restrict__ x2,
    float* __restrict__ out) {
  __shared__ float lds[2 * kBufDw];  // 24 KB

  // XCD swizzle: grid = 8*128, blockIdx&7 -> batch (one batch per XCD),
  // consecutive h-pairs land on the same XCD for x2 row reuse in L2.
  const int bb = blockIdx.x & 7;
  const int hp = blockIdx.x >> 3;   // 0..127
  const int tid = (int)threadIdx.x;
  const int wv = tid >> 6;          // wave = dx
  const int lane = tid & 63;
  const int half = lane >> 5;       // 0: row h0, 1: row h1
  const int lh = lane & 31;
  const int h = 2 * hp + half;
  const int w0 = lh * 8;

  const bool hasL = (lh > 0);
  const bool hasR = (lh < 31);
  const float4 z = make_float4(0.f, 0.f, 0.f, 0.f);

  // ---- staging role: slot s -> row r=s>>6 (0..11), 16B-block b=s&63 ----
  // wave wv writes row wv (contiguous 64 slots); waves 0-2 also rows 9-11.
  const size_t chanBase = (size_t)(bb * kC) * kH;  // in rows

  const int r0s = tid >> 6, b0s = tid & 63;
  const float* src0;
  bool v0;
  if (r0s < 2) {  // x1 rows h0, h1
    v0 = true;
    src0 = x1 + (chanBase + (size_t)(2 * hp + r0s)) * kW + b0s * 4;
  } else {        // x2 row rr = 2hp + r - 6
    const int rr = 2 * hp + r0s - 6;
    v0 = (rr >= 0 && rr < kH);
    src0 = x2 + (chanBase + (size_t)(v0 ? rr : 0)) * kW + b0s * 4;
  }
  const int w0i = r0s * kW + swz(b0s) * 4;

  const bool have1 = (tid < 192);   // slots 576..767 -> rows 9..11
  const int r1s = (576 + tid) >> 6, b1s = (576 + tid) & 63;
  const float* src1 = x2;
  bool v1 = false;
  int w1i = 0;
  if (have1) {
    const int rr = 2 * hp + r1s - 6;
    v1 = (rr >= 0 && rr < kH);
    src1 = x2 + (chanBase + (size_t)(v1 ? rr : 0)) * kW + b1s * 4;
    w1i = r1s * kW + swz(b1s) * 4;
  }

  // ---- per-lane LDS read offsets (dwords, buf0) ----
  const int a0i = half * kW + swz(2 * lh) * 4;
  const int a1i = half * kW + swz(2 * lh + 1) * 4;
  const int Rr = (2 + half + wv) * kW;           // x2 row for this (half,dx)
  const int t0i = Rr + swz((2 * lh - 1) & 63) * 4;
  const int t1i = Rr + swz(2 * lh) * 4;
  const int t2i = Rr + swz(2 * lh + 1) * 4;
  const int t3i = Rr + swz((2 * lh + 2) & 63) * 4;

  float acc[kD][8];
#pragma unroll
  for (int dy = 0; dy < kD; ++dy)
#pragma unroll
    for (int j = 0; j < 8; ++j) acc[dy][j] = 0.0f;

  // prologue: stage channel 0 into buf0
  {
    const float4 g0 = v0 ? *reinterpret_cast<const float4*>(src0) : z;
    *reinterpret_cast<float4*>(&lds[w0i]) = g0;
    if (have1) {
      const float4 g1 = v1 ? *reinterpret_cast<const float4*>(src1) : z;
      *reinterpret_cast<float4*>(&lds[w1i]) = g1;
    }
    src0 += kCS;
    src1 += kCS;
  }
  __syncthreads();

#pragma unroll 2
  for (int c = 0; c < kC; ++c) {
    const int bo = (c & 1) ? kBufDw : 0;
    const int bo2 = (c & 1) ? 0 : kBufDw;
    const bool more = (c + 1 < kC);

    // issue next channel's global loads early (hidden under LDS+FMA)
    float4 n0 = z, n1 = z;
    if (more) {
      n0 = v0 ? *reinterpret_cast<const float4*>(src0) : z;
      if (have1) n1 = v1 ? *reinterpret_cast<const float4*>(src1) : z;
      src0 += kCS;
      src1 += kCS;
    }

    const float4 A0 = *reinterpret_cast<const float4*>(&lds[bo + a0i]);
    const float4 A1 = *reinterpret_cast<const float4*>(&lds[bo + a1i]);
    const float4 T0 = hasL ? *reinterpret_cast<const float4*>(&lds[bo + t0i]) : z;
    const float4 T1 = *reinterpret_cast<const float4*>(&lds[bo + t1i]);
    const float4 T2 = *reinterpret_cast<const float4*>(&lds[bo + t2i]);
    const float4 T3 = hasR ? *reinterpret_cast<const float4*>(&lds[bo + t3i]) : z;

    const float av[8] = {A0.x, A0.y, A0.z, A0.w, A1.x, A1.y, A1.z, A1.w};
    const float t[16] = {T0.x, T0.y, T0.z, T0.w, T1.x, T1.y, T1.z, T1.w,
                         T2.x, T2.y, T2.z, T2.w, T3.x, T3.y, T3.z, T3.w};
    // output col w0+j, shift dy: x2 col = w0+j+dy-4 -> t[j+dy] (t[0]=w0-4)
#pragma unroll
    for (int dy = 0; dy < kD; ++dy)
#pragma unroll
      for (int j = 0; j < 8; ++j)
        acc[dy][j] = fmaf(av[j], t[dy + j], acc[dy][j]);

    if (more) {
      *reinterpret_cast<float4*>(&lds[bo2 + w0i]) = n0;
      if (have1) *reinterpret_cast<float4*>(&lds[bo2 + w1i]) = n1;
      __syncthreads();
    }
  }

  const float inv = 1.0f / (float)kC;
  float* po = out + (((size_t)bb * (kD * kD) + wv * kD) * kH + h) * kW + w0;
#pragma unroll
  for (int dy = 0; dy < kD; ++dy) {
    const float4 o0 = make_float4(acc[dy][0] * inv, acc[dy][1] * inv,
                                  acc[dy][2] * inv, acc[dy][3] * inv);
    const float4 o1 = make_float4(acc[dy][4] * inv, acc[dy][5] * inv,
                                  acc[dy][6] * inv, acc[dy][7] * inv);
    *reinterpret_cast<float4*>(po) = o0;
    *reinterpret_cast<float4*>(po + 4) = o1;
    po += (size_t)kH * kW;
  }
}

extern "C" void kernel_launch(void* const* d_in, const int* in_sizes, int n_in,
                              void* d_out, int out_size, void* d_ws, size_t ws_size,
                              hipStream_t stream) {
  const float* x1 = (const float*)d_in[0];
  const float* x2 = (const float*)d_in[1];
  float* out = (float*)d_out;
  const int grid = kB * (kH / 2);  // 1024 blocks, 9 waves each
  corr_kernel<<<grid, 576, 0, stream>>>(x1, x2, out);
}